// Round 1
// baseline (416.056 us; speedup 1.0000x reference)
//
#include <hip/hip_runtime.h>
#include <hip/hip_fp16.h>

// Problem constants
#define S_LEN 128
#define DLOG  128
#define DMEM  16
#define SO    120
#define HDIM  256

// ---------------------------------------------------------------------------
// K1: Q = x@Wq^T + bq,  K = x@Wk^T + bk   (tiny)
// ---------------------------------------------------------------------------
__global__ __launch_bounds__(128) void qk_kernel(
    const float* __restrict__ xl, const float* __restrict__ Wq,
    const float* __restrict__ bq, const float* __restrict__ Wk,
    const float* __restrict__ bk, float* __restrict__ Q, float* __restrict__ K) {
  int bj = blockIdx.x, o = threadIdx.x;
  __shared__ float xs[128];
  xs[o] = xl[bj * 128 + o];
  __syncthreads();
  float aq = bq[o], ak = bk[o];
  const float* wq = Wq + o * 128;
  const float* wk = Wk + o * 128;
  #pragma unroll 4
  for (int d = 0; d < 128; ++d) {
    float x = xs[d];
    aq = fmaf(x, wq[d], aq);
    ak = fmaf(x, wk[d], ak);
  }
  Q[bj * 128 + o] = aq;
  K[bj * 128 + o] = ak;
}

// ---------------------------------------------------------------------------
// K2: attn[b,j,i] = softmax_i( Q[b,j].K[b,i] / sqrt(128) )
// ---------------------------------------------------------------------------
__global__ __launch_bounds__(128) void attn_kernel(
    const float* __restrict__ Q, const float* __restrict__ K,
    float* __restrict__ attn) {
  int bj = blockIdx.x, b = bj >> 7, i = threadIdx.x;
  __shared__ float qs[128];
  __shared__ float red[128];
  qs[i] = Q[bj * 128 + i];
  __syncthreads();
  const float* kr = K + (b * 128 + i) * 128;
  float s = 0.f;
  #pragma unroll 4
  for (int d = 0; d < 128; ++d) s = fmaf(qs[d], kr[d], s);
  s *= 0.08838834764831845f;  // 1/sqrt(128)
  red[i] = s;
  __syncthreads();
  for (int off = 64; off; off >>= 1) {
    if (i < off) red[i] = fmaxf(red[i], red[i + off]);
    __syncthreads();
  }
  float m = red[0];
  __syncthreads();
  float e = expf(s - m);
  red[i] = e;
  __syncthreads();
  for (int off = 64; off; off >>= 1) {
    if (i < off) red[i] += red[i + off];
    __syncthreads();
  }
  attn[(size_t)bj * 128 + i] = e / red[0];
}

// ---------------------------------------------------------------------------
// K3: h[p][o] = tanh(delta[p] . W1[o] + b1[o]) written into the T_all region
//     (layout [65536][256] fp32 == exactly the h matrix; overwritten by K4)
// block: 256 thr, handles 32 pairs x 128 outputs. W1 half in LDS fp16.
// ---------------------------------------------------------------------------
#define W1H 132
__global__ __launch_bounds__(256) void h_kernel(
    const float* __restrict__ xl, const float* __restrict__ W1,
    const float* __restrict__ b1, float* __restrict__ hout) {
  __shared__ __half w1s[128 * W1H];
  __shared__ float dl[32 * W1H];
  int t = threadIdx.x;
  int blk = blockIdx.x;
  int bj = blk >> 3;
  int b = bj >> 7;
  int sub = blk & 7;
  int i0 = (sub & 3) * 32;
  int o0 = (sub >> 2) * 128;
  for (int idx = t; idx < 128 * 128; idx += 256) {
    int o = idx >> 7, d = idx & 127;
    w1s[o * W1H + d] = __float2half(W1[(o0 + o) * 128 + d]);
  }
  const float* xj = xl + bj * 128;
  const float* xi = xl + (b * 128 + i0) * 128;
  for (int idx = t; idx < 32 * 128; idx += 256) {
    int ii = idx >> 7, d = idx & 127;
    dl[ii * W1H + d] = xj[d] - xi[ii * 128 + d];
  }
  __syncthreads();
  int lane = t & 63, w = t >> 6;
  float acc[2][8];
  #pragma unroll
  for (int m = 0; m < 2; m++)
    #pragma unroll
    for (int pp = 0; pp < 8; pp++) acc[m][pp] = 0.f;

  for (int d = 0; d < 128; d += 4) {
    float4 dv[8];
    #pragma unroll
    for (int pp = 0; pp < 8; pp++)
      dv[pp] = *(const float4*)&dl[(8 * w + pp) * W1H + d];
    #pragma unroll
    for (int m = 0; m < 2; m++) {
      const __half* wp = &w1s[(lane + 64 * m) * W1H + d];
      float2 f01 = __half22float2(*(const __half2*)(wp));
      float2 f23 = __half22float2(*(const __half2*)(wp + 2));
      #pragma unroll
      for (int pp = 0; pp < 8; pp++) {
        acc[m][pp] = fmaf(f01.x, dv[pp].x,
                     fmaf(f01.y, dv[pp].y,
                     fmaf(f23.x, dv[pp].z,
                     fmaf(f23.y, dv[pp].w, acc[m][pp]))));
      }
    }
  }
  #pragma unroll
  for (int m = 0; m < 2; m++) {
    int o = o0 + lane + 64 * m;
    float bb = b1[o];
    #pragma unroll
    for (int pp = 0; pp < 8; pp++) {
      size_t p = (size_t)bj * 128 + i0 + 8 * w + pp;
      hout[p * 256 + o] = tanhf(acc[m][pp] + bb);
    }
  }
}

// ---------------------------------------------------------------------------
// K4: lie = h@W2^T + b2 ; skew scatter ; T = expm(skew) (scale&square +
// order-14 Taylor). One wave handles 8 pairs; in-place h -> T overwrite.
// Row broadcasts inside the 16x16 matmul via DPP quad_perm (r = lane>>2).
// ---------------------------------------------------------------------------
#define W2H 132

template <int SEL>
__device__ __forceinline__ float qbcast(float v) {
  return __int_as_float(__builtin_amdgcn_mov_dpp(
      __float_as_int(v), SEL * 0x55, 0xF, 0xF, true));
}

// n = P_row_tile @ Ac   where lane holds P[r][4a..4a+3], Ac[k][j]=A[k][4a+j]
__device__ __forceinline__ void quad_matmul(const float (&P)[4],
                                            const float (&Ac)[16][4],
                                            float (&n)[4]) {
  n[0] = n[1] = n[2] = n[3] = 0.f;
  {
    float g0 = qbcast<0>(P[0]), g1 = qbcast<0>(P[1]), g2 = qbcast<0>(P[2]), g3 = qbcast<0>(P[3]);
    #pragma unroll
    for (int j = 0; j < 4; j++)
      n[j] = fmaf(g0, Ac[0][j], fmaf(g1, Ac[1][j], fmaf(g2, Ac[2][j], fmaf(g3, Ac[3][j], n[j]))));
  }
  {
    float g0 = qbcast<1>(P[0]), g1 = qbcast<1>(P[1]), g2 = qbcast<1>(P[2]), g3 = qbcast<1>(P[3]);
    #pragma unroll
    for (int j = 0; j < 4; j++)
      n[j] = fmaf(g0, Ac[4][j], fmaf(g1, Ac[5][j], fmaf(g2, Ac[6][j], fmaf(g3, Ac[7][j], n[j]))));
  }
  {
    float g0 = qbcast<2>(P[0]), g1 = qbcast<2>(P[1]), g2 = qbcast<2>(P[2]), g3 = qbcast<2>(P[3]);
    #pragma unroll
    for (int j = 0; j < 4; j++)
      n[j] = fmaf(g0, Ac[8][j], fmaf(g1, Ac[9][j], fmaf(g2, Ac[10][j], fmaf(g3, Ac[11][j], n[j]))));
  }
  {
    float g0 = qbcast<3>(P[0]), g1 = qbcast<3>(P[1]), g2 = qbcast<3>(P[2]), g3 = qbcast<3>(P[3]);
    #pragma unroll
    for (int j = 0; j < 4; j++)
      n[j] = fmaf(g0, Ac[12][j], fmaf(g1, Ac[13][j], fmaf(g2, Ac[14][j], fmaf(g3, Ac[15][j], n[j]))));
  }
}

__global__ __launch_bounds__(256) void expm_kernel(
    const float* __restrict__ W2g, const float* __restrict__ b2,
    float* __restrict__ Tg) {
  __shared__ __half w2s[120 * W2H];
  __shared__ float pbuf[4][336];    // per-wave 16x16 tile, row stride 20
  __shared__ float liebuf[4][128];  // per-wave lie scatter buffer
  int t = threadIdx.x, lane = t & 63;
  int wu = __builtin_amdgcn_readfirstlane(t >> 6);
  int base = blockIdx.x * 32 + wu * 8;
  bool has2 = lane < 56;
  int o2 = has2 ? (64 + lane) : lane;

  // ---- lie GEMV for 8 pairs, W2 streamed through LDS in two k-halves ----
  float a0[8], a1[8];
  #pragma unroll
  for (int pp = 0; pp < 8; pp++) { a0[pp] = 0.f; a1[pp] = 0.f; }
  for (int kh = 0; kh < 2; ++kh) {
    __syncthreads();
    for (int idx = t; idx < 120 * 128; idx += 256) {
      int o = idx >> 7, kk = idx & 127;
      w2s[o * W2H + kk] = __float2half(W2g[o * 256 + kh * 128 + kk]);
    }
    __syncthreads();
    const __half* wr0 = &w2s[lane * W2H];
    const __half* wr1 = &w2s[o2 * W2H];
    for (int k = 0; k < 128; k += 4) {
      float2 p0 = __half22float2(*(const __half2*)(wr0 + k));
      float2 p1 = __half22float2(*(const __half2*)(wr0 + k + 2));
      float2 q0 = __half22float2(*(const __half2*)(wr1 + k));
      float2 q1 = __half22float2(*(const __half2*)(wr1 + k + 2));
      #pragma unroll
      for (int pp = 0; pp < 8; pp++) {
        // wave-uniform address -> scalar loads; h lives in the T region
        const float4 hv = *(const float4*)(Tg + ((size_t)(base + pp) << 8) + kh * 128 + k);
        a0[pp] = fmaf(p0.x, hv.x, fmaf(p0.y, hv.y, fmaf(p1.x, hv.z, fmaf(p1.y, hv.w, a0[pp]))));
        a1[pp] = fmaf(q0.x, hv.x, fmaf(q0.y, hv.y, fmaf(q1.x, hv.z, fmaf(q1.y, hv.w, a1[pp]))));
      }
    }
  }
  float bias1 = b2[lane];
  float bias2 = has2 ? b2[64 + lane] : 0.f;
  int r = lane >> 2, a = lane & 3;
  float* pb = pbuf[wu];
  float* lb = liebuf[wu];

  for (int pp = 0; pp < 8; ++pp) {
    float lie1 = a0[pp] + bias1;
    float lie2 = has2 ? (a1[pp] + bias2) : 0.f;
    // ||A||_2 <= sqrt(sum lie^2)  (= ||A||_F / sqrt(2))
    float s2 = lie1 * lie1 + lie2 * lie2;
    #pragma unroll
    for (int off = 1; off < 64; off <<= 1) s2 += __shfl_xor(s2, off, 64);
    float bound = sqrtf(s2);
    int s = 0;
    while (bound > 2.0f && s < 14) { bound *= 0.5f; s++; }
    float sc = ldexpf(1.0f, -s);

    // scatter lie for skew build
    lb[lane] = lie1;
    if (has2) lb[64 + lane] = lie2;
    __threadfence_block();

    // build scaled skew tile: A[r][4a+j]
    float At[4];
    #pragma unroll
    for (int j = 0; j < 4; j++) {
      int c = 4 * a + j;
      int rr = min(r, c), cc = max(r, c);
      int li = (cc > rr) ? (15 * rr - (rr * (rr - 1)) / 2 + cc - rr - 1) : 0;
      float lv = lb[li];
      At[j] = (c == r) ? 0.f : ((c > r) ? lv : -lv) * sc;
    }

    // tile -> LDS, read column strip Ac[k][j] = A[k][4a+j]
    __threadfence_block();
    *(float4*)&pb[r * 20 + a * 4] = make_float4(At[0], At[1], At[2], At[3]);
    __threadfence_block();
    float Ac[16][4];
    #pragma unroll
    for (int kk = 0; kk < 16; kk++) {
      float4 cv = *(const float4*)&pb[kk * 20 + a * 4];
      Ac[kk][0] = cv.x; Ac[kk][1] = cv.y; Ac[kk][2] = cv.z; Ac[kk][3] = cv.w;
    }

    // E = I + A ; Taylor terms 2..14
    float P[4], E[4];
    #pragma unroll
    for (int j = 0; j < 4; j++) {
      P[j] = At[j];
      E[j] = At[j] + ((4 * a + j == r) ? 1.f : 0.f);
    }
    #pragma unroll
    for (int k = 2; k <= 14; k++) {
      float n[4];
      quad_matmul(P, Ac, n);
      const float rk = 1.0f / (float)k;
      #pragma unroll
      for (int j = 0; j < 4; j++) { P[j] = n[j] * rk; E[j] += P[j]; }
    }
    // squarings
    for (int q = 0; q < s; ++q) {
      __threadfence_block();
      *(float4*)&pb[r * 20 + a * 4] = make_float4(E[0], E[1], E[2], E[3]);
      __threadfence_block();
      #pragma unroll
      for (int kk = 0; kk < 16; kk++) {
        float4 cv = *(const float4*)&pb[kk * 20 + a * 4];
        Ac[kk][0] = cv.x; Ac[kk][1] = cv.y; Ac[kk][2] = cv.z; Ac[kk][3] = cv.w;
      }
      float n[4];
      quad_matmul(E, Ac, n);
      #pragma unroll
      for (int j = 0; j < 4; j++) E[j] = n[j];
    }
    // store T (overwrites h slot of this pair; h fully consumed above)
    *(float4*)(Tg + ((size_t)(base + pp) << 8) + lane * 4) =
        make_float4(E[0], E[1], E[2], E[3]);
  }
}

// ---------------------------------------------------------------------------
// K5: settled[b,j] = sum_i attn[b,j,i] * (T[b,j,i] @ xm[b,i]);
//     out = settled @ Wo^T + bo
// ---------------------------------------------------------------------------
__global__ __launch_bounds__(256) void settle_kernel(
    const float* __restrict__ Tg, const float* __restrict__ attn,
    const float* __restrict__ xm, const float* __restrict__ Wo,
    const float* __restrict__ bo, float* __restrict__ outp) {
  int bj = blockIdx.x, b = bj >> 7;
  int t = threadIdx.x, lane = t & 63;
  int wu = __builtin_amdgcn_readfirstlane(t >> 6);
  int r = lane >> 2, a = lane & 3;
  float pacc = 0.f;
  for (int ii = 0; ii < 32; ++ii) {
    int i = wu * 32 + ii;
    size_t p = (size_t)bj * 128 + i;
    const float4 tv = *(const float4*)(Tg + (p << 8) + lane * 4);
    const float* xv = xm + (b * 128 + i) * 16;
    float aw = attn[p];
    float y = tv.x * xv[4 * a] + tv.y * xv[4 * a + 1] +
              tv.z * xv[4 * a + 2] + tv.w * xv[4 * a + 3];
    y += __shfl_xor(y, 1, 64);
    y += __shfl_xor(y, 2, 64);
    pacc = fmaf(aw, y, pacc);
  }
  __shared__ float sred[4][16];
  __shared__ float sfin[16];
  if (a == 0) sred[wu][r] = pacc;
  __syncthreads();
  if (t < 16) sfin[t] = sred[0][t] + sred[1][t] + sred[2][t] + sred[3][t];
  __syncthreads();
  if (t < 16) {
    float o = bo[t];
    const float* wr = Wo + t * 16;
    #pragma unroll
    for (int c = 0; c < 16; c++) o = fmaf(wr[c], sfin[c], o);
    outp[bj * 16 + t] = o;
  }
}

// ---------------------------------------------------------------------------
extern "C" void kernel_launch(void* const* d_in, const int* in_sizes, int n_in,
                              void* d_out, int out_size, void* d_ws,
                              size_t ws_size, hipStream_t stream) {
  const float* xl = (const float*)d_in[0];
  const float* xm = (const float*)d_in[1];
  const float* Wq = (const float*)d_in[2];
  const float* bq = (const float*)d_in[3];
  const float* Wk = (const float*)d_in[4];
  const float* bk = (const float*)d_in[5];
  const float* W1 = (const float*)d_in[6];
  const float* b1 = (const float*)d_in[7];
  const float* W2 = (const float*)d_in[8];
  const float* b2 = (const float*)d_in[9];
  const float* Wo = (const float*)d_in[10];
  const float* bo = (const float*)d_in[11];
  float* outp = (float*)d_out;
  float* Tg = outp + 8192;  // [65536][256] region: holds h, then T_all
  float* wsf = (float*)d_ws;
  float* Q = wsf;
  float* K = wsf + 65536;
  float* attn = wsf + 131072;  // 768 KB of ws used

  hipLaunchKernelGGL(qk_kernel, dim3(512), dim3(128), 0, stream, xl, Wq, bq, Wk, bk, Q, K);
  hipLaunchKernelGGL(attn_kernel, dim3(512), dim3(128), 0, stream, Q, K, attn);
  hipLaunchKernelGGL(h_kernel, dim3(4096), dim3(256), 0, stream, xl, W1, b1, Tg);
  hipLaunchKernelGGL(expm_kernel, dim3(2048), dim3(256), 0, stream, W2, b2, Tg);
  hipLaunchKernelGGL(settle_kernel, dim3(512), dim3(256), 0, stream, Tg, attn, xm, Wo, bo, outp);
}

// Round 3
// 339.546 us; speedup vs baseline: 1.2253x; 1.2253x over previous
//
#include <hip/hip_runtime.h>
#include <hip/hip_fp16.h>

// Problem constants
#define S_LEN 128
#define DLOG  128
#define DMEM  16
#define SO    120
#define HDIM  256

typedef _Float16 v8h __attribute__((ext_vector_type(8)));
typedef __fp16 v2hf __attribute__((ext_vector_type(2)));
typedef float v4f __attribute__((ext_vector_type(4)));

// ---------------------------------------------------------------------------
// K1: Q = x@Wq^T + bq,  K = x@Wk^T + bk   (tiny)
// ---------------------------------------------------------------------------
__global__ __launch_bounds__(128) void qk_kernel(
    const float* __restrict__ xl, const float* __restrict__ Wq,
    const float* __restrict__ bq, const float* __restrict__ Wk,
    const float* __restrict__ bk, float* __restrict__ Q, float* __restrict__ K) {
  int bj = blockIdx.x, o = threadIdx.x;
  __shared__ float xs[128];
  xs[o] = xl[bj * 128 + o];
  __syncthreads();
  float aq = bq[o], ak = bk[o];
  const float* wq = Wq + o * 128;
  const float* wk = Wk + o * 128;
  #pragma unroll 4
  for (int d = 0; d < 128; ++d) {
    float x = xs[d];
    aq = fmaf(x, wq[d], aq);
    ak = fmaf(x, wk[d], ak);
  }
  Q[bj * 128 + o] = aq;
  K[bj * 128 + o] = ak;
}

// ---------------------------------------------------------------------------
// K2: attn[b,j,i] = softmax_i( Q[b,j].K[b,i] / sqrt(128) )
// ---------------------------------------------------------------------------
__global__ __launch_bounds__(128) void attn_kernel(
    const float* __restrict__ Q, const float* __restrict__ K,
    float* __restrict__ attn) {
  int bj = blockIdx.x, b = bj >> 7, i = threadIdx.x;
  __shared__ float qs[128];
  __shared__ float red[128];
  qs[i] = Q[bj * 128 + i];
  __syncthreads();
  const float* kr = K + (b * 128 + i) * 128;
  float s = 0.f;
  #pragma unroll 4
  for (int d = 0; d < 128; ++d) s = fmaf(qs[d], kr[d], s);
  s *= 0.08838834764831845f;  // 1/sqrt(128)
  red[i] = s;
  __syncthreads();
  for (int off = 64; off; off >>= 1) {
    if (i < off) red[i] = fmaxf(red[i], red[i + off]);
    __syncthreads();
  }
  float m = red[0];
  __syncthreads();
  float e = expf(s - m);
  red[i] = e;
  __syncthreads();
  for (int off = 64; off; off >>= 1) {
    if (i < off) red[i] += red[i + off];
    __syncthreads();
  }
  attn[(size_t)bj * 128 + i] = e / red[0];
}

// ---------------------------------------------------------------------------
// K3: h[p][o] = tanh(delta[p] . W1[o] + b1[o]) written into the T_all region
// ---------------------------------------------------------------------------
#define W1H 132
__global__ __launch_bounds__(256) void h_kernel(
    const float* __restrict__ xl, const float* __restrict__ W1,
    const float* __restrict__ b1, float* __restrict__ hout) {
  __shared__ __half w1s[128 * W1H];
  __shared__ float dl[32 * W1H];
  int t = threadIdx.x;
  int blk = blockIdx.x;
  int bj = blk >> 3;
  int b = bj >> 7;
  int sub = blk & 7;
  int i0 = (sub & 3) * 32;
  int o0 = (sub >> 2) * 128;
  for (int idx = t; idx < 128 * 128; idx += 256) {
    int o = idx >> 7, d = idx & 127;
    w1s[o * W1H + d] = __float2half(W1[(o0 + o) * 128 + d]);
  }
  const float* xj = xl + bj * 128;
  const float* xi = xl + (b * 128 + i0) * 128;
  for (int idx = t; idx < 32 * 128; idx += 256) {
    int ii = idx >> 7, d = idx & 127;
    dl[ii * W1H + d] = xj[d] - xi[ii * 128 + d];
  }
  __syncthreads();
  int lane = t & 63, w = t >> 6;
  float acc[2][8];
  #pragma unroll
  for (int m = 0; m < 2; m++)
    #pragma unroll
    for (int pp = 0; pp < 8; pp++) acc[m][pp] = 0.f;

  for (int d = 0; d < 128; d += 4) {
    float4 dv[8];
    #pragma unroll
    for (int pp = 0; pp < 8; pp++)
      dv[pp] = *(const float4*)&dl[(8 * w + pp) * W1H + d];
    #pragma unroll
    for (int m = 0; m < 2; m++) {
      const __half* wp = &w1s[(lane + 64 * m) * W1H + d];
      float2 f01 = __half22float2(*(const __half2*)(wp));
      float2 f23 = __half22float2(*(const __half2*)(wp + 2));
      #pragma unroll
      for (int pp = 0; pp < 8; pp++) {
        acc[m][pp] = fmaf(f01.x, dv[pp].x,
                     fmaf(f01.y, dv[pp].y,
                     fmaf(f23.x, dv[pp].z,
                     fmaf(f23.y, dv[pp].w, acc[m][pp]))));
      }
    }
  }
  #pragma unroll
  for (int m = 0; m < 2; m++) {
    int o = o0 + lane + 64 * m;
    float bb = b1[o];
    #pragma unroll
    for (int pp = 0; pp < 8; pp++) {
      size_t p = (size_t)bj * 128 + i0 + 8 * w + pp;
      hout[p * 256 + o] = tanhf(acc[m][pp] + bb);
    }
  }
}

// ---------------------------------------------------------------------------
// K4 (MFMA rewrite): lie = h@W2^T + b2 via mfma f16 (A=h hi/lo split, B=W2
// f16); then per-pair T = expm(skew) with the K-concat trick:
//   A_cat=[Ahi|Alo] (16x32 A-operand), B=[P;P] -> 2 MFMAs = exact A*P.
// 16 pairs/wave, pairs processed in chunks of 2.  LDS: W2 stage (phase A)
// unioned with per-wave lie/Pt/Erow buffers (phase B).
// ---------------------------------------------------------------------------
#define LIE_STR 132
#define PB_STR  20
#define WAVE_LDS 13568  // 8448 (lie 16x132 f32) + 2560 (Pt x2) + 2560 (Er x2)

__device__ __forceinline__ void split8(const float* x, v8h& hi, v8h& lo) {
  union U { v8h v; v2hf p[4]; } H, L;
  #pragma unroll
  for (int i = 0; i < 4; ++i) {
    float a = x[2 * i], b = x[2 * i + 1];
    v2hf h = __builtin_amdgcn_cvt_pkrtz(a, b);
    float ra = (float)h[0], rb = (float)h[1];
    v2hf l = __builtin_amdgcn_cvt_pkrtz(a - ra, b - rb);
    H.p[i] = h;
    L.p[i] = l;
  }
  hi = H.v;
  lo = L.v;
}

__device__ __forceinline__ int lie_idx(int rr, int cc) {
  // upper-tri (rr<cc) row-major index, matches np.triu_indices(16,1)
  return 15 * rr - ((rr * (rr - 1)) >> 1) + cc - rr - 1;
}

__global__ __launch_bounds__(256) void expm_kernel(
    const float* __restrict__ W2g, const float* __restrict__ b2g,
    float* __restrict__ Tg) {
  __shared__ char ldsraw[54272] __attribute__((aligned(16)));
  _Float16* w2t = (_Float16*)ldsraw;  // [128 n][136 k] f16, phase A only

  int t = threadIdx.x, lane = t & 63;
  int wu = __builtin_amdgcn_readfirstlane(t >> 6);
  int base = (blockIdx.x * 4 + wu) * 16;  // 16 pairs per wave
  const int nn = lane & 15;               // column role (B/C) & row role (A)
  const int q = lane >> 4;
  const int b8 = (q & 1) * 8;

  char* wb = ldsraw + (size_t)wu * WAVE_LDS;
  float* lieb = (float*)wb;              // [16][132] f32
  float* PtB = (float*)(wb + 8448);      // 2 x [16 col][20] f32 (col-major P/E)
  float* ErB = (float*)(wb + 8448 + 2560);  // 2 x [16 row][20] f32 (row-major E)

  // ================= phase A: lie GEMM =================
  v4f acc[8];
  #pragma unroll
  for (int tt = 0; tt < 8; ++tt) acc[tt] = (v4f){0.f, 0.f, 0.f, 0.f};

  const float* hrow = Tg + ((size_t)(base + nn) << 8);
  for (int khalf = 0; khalf < 2; ++khalf) {
    __syncthreads();
    for (int idx = t; idx < 120 * 128; idx += 256) {
      int o = idx >> 7, kk = idx & 127;
      w2t[o * 136 + kk] = (_Float16)W2g[o * 256 + khalf * 128 + kk];
    }
    for (int idx = t; idx < 8 * 136; idx += 256) w2t[120 * 136 + idx] = (_Float16)0.f;
    __syncthreads();
    #pragma unroll
    for (int ks = 0; ks < 4; ++ks) {
      int kg = khalf * 128 + ks * 32 + 8 * q;
      float x[8];
      float4 u0 = *(const float4*)(hrow + kg);
      float4 u1 = *(const float4*)(hrow + kg + 4);
      x[0] = u0.x; x[1] = u0.y; x[2] = u0.z; x[3] = u0.w;
      x[4] = u1.x; x[5] = u1.y; x[6] = u1.z; x[7] = u1.w;
      v8h ahi, alo;
      split8(x, ahi, alo);
      #pragma unroll
      for (int tt = 0; tt < 8; ++tt) {
        const v8h bf = *(const v8h*)(w2t + (16 * tt + nn) * 136 + ks * 32 + 8 * q);
        acc[tt] = __builtin_amdgcn_mfma_f32_16x16x32_f16(alo, bf, acc[tt], 0, 0, 0);
        acc[tt] = __builtin_amdgcn_mfma_f32_16x16x32_f16(ahi, bf, acc[tt], 0, 0, 0);
      }
    }
  }
  __syncthreads();  // all waves done with w2t before liebuf overwrites it

  // bias + scatter lie to per-wave LDS ([pair][n], rows m=(lane>>4)*4+reg)
  #pragma unroll
  for (int tt = 0; tt < 8; ++tt) {
    int n16 = 16 * tt + nn;
    float bb = (n16 < 120) ? b2g[n16] : 0.f;
    #pragma unroll
    for (int reg = 0; reg < 4; ++reg) {
      int pr = 4 * q + reg;
      float v = (n16 < 120) ? (acc[tt][reg] + bb) : 0.f;
      lieb[pr * LIE_STR + n16] = v;
    }
  }
  asm volatile("s_waitcnt lgkmcnt(0)" ::: "memory");

  // ================= phase B: per-pair expm =================
  for (int cc = 0; cc < 8; ++cc) {
    int sA[2];
    v8h Acat[2];
    v4f E[2];
    #pragma unroll
    for (int j = 0; j < 2; ++j) {
      int p = 2 * cc + j;
      const float* lp = lieb + p * LIE_STR;
      float v0 = lp[lane], v1 = lp[lane + 64];
      float s2 = v0 * v0 + v1 * v1;
      #pragma unroll
      for (int off = 1; off < 64; off <<= 1) s2 += __shfl_xor(s2, off, 64);
      float bound = sqrtf(s2);  // ||A||_2 <= sqrt(sum lie^2) for skew
      int s = 0;
      while (bound > 1.0f && s < 12) { bound *= 0.5f; s++; }
      sA[j] = s;
      float sc = ldexpf(1.0f, -s);

      // A-operand frag: A_cat[m][k]: q<2 -> Ahi cols b8..b8+7, q>=2 -> Alo
      float av[8];
      #pragma unroll
      for (int jj = 0; jj < 8; ++jj) {
        int c = b8 + jj;
        int rr = min(nn, c), c2 = max(nn, c);
        int li = (c == nn) ? 0 : lie_idx(rr, c2);
        float lv = lp[li];
        av[jj] = (c == nn) ? 0.f : ((c > nn) ? lv : -lv) * sc;
      }
      v8h hi, lo;
      split8(av, hi, lo);
      Acat[j] = (q < 2) ? hi : lo;

      // E = I + A (C-layout: rows 4q+reg, col nn);  P1 = A -> Pt (col-major)
      float Pw[4], e4[4];
      #pragma unroll
      for (int reg = 0; reg < 4; ++reg) {
        int r = 4 * q + reg, c = nn;
        int rr = min(r, c), c2 = max(r, c);
        int li = (r == c) ? 0 : lie_idx(rr, c2);
        float lv = lp[li];
        float v = (r == c) ? 0.f : ((c > r) ? lv : -lv) * sc;
        Pw[reg] = v;
        e4[reg] = v + ((r == c) ? 1.f : 0.f);
      }
      float* Pt_p = PtB + j * 320;
      *(float4*)(Pt_p + nn * PB_STR + 4 * q) = make_float4(Pw[0], Pw[1], Pw[2], Pw[3]);
      v4f ee = {e4[0], e4[1], e4[2], e4[3]};
      E[j] = ee;
    }
    asm volatile("s_waitcnt lgkmcnt(0)" ::: "memory");

    // Taylor terms k=2..9 (theta=1.0, remainder ~3e-7)
    #pragma unroll
    for (int k = 2; k <= 9; ++k) {
      const float rk = 1.0f / (float)k;
      #pragma unroll
      for (int j = 0; j < 2; ++j) {
        float* Pt_p = PtB + j * 320;
        float4 r0 = *(const float4*)(Pt_p + nn * PB_STR + b8);
        float4 r1 = *(const float4*)(Pt_p + nn * PB_STR + b8 + 4);
        float x[8] = {r0.x, r0.y, r0.z, r0.w, r1.x, r1.y, r1.z, r1.w};
        v8h bh, bl;
        split8(x, bh, bl);
        v4f z = {0.f, 0.f, 0.f, 0.f};
        v4f c4 = __builtin_amdgcn_mfma_f32_16x16x32_f16(Acat[j], bl, z, 0, 0, 0);
        c4 = __builtin_amdgcn_mfma_f32_16x16x32_f16(Acat[j], bh, c4, 0, 0, 0);
        c4 = c4 * rk;  // P_k
        E[j] += c4;
        *(float4*)(Pt_p + nn * PB_STR + 4 * q) = make_float4(c4[0], c4[1], c4[2], c4[3]);
      }
      asm volatile("s_waitcnt lgkmcnt(0)" ::: "memory");
    }

    // squarings (wave-uniform per pair)
    int smax = max(sA[0], sA[1]);
    for (int it = 0; it < smax; ++it) {
      #pragma unroll
      for (int j = 0; j < 2; ++j) {
        if (it < sA[j]) {
          float* Pt_p = PtB + j * 320;
          float* Er_p = ErB + j * 320;
          #pragma unroll
          for (int reg = 0; reg < 4; ++reg)
            Er_p[(4 * q + reg) * PB_STR + nn] = E[j][reg];
          *(float4*)(Pt_p + nn * PB_STR + 4 * q) =
              make_float4(E[j][0], E[j][1], E[j][2], E[j][3]);
          asm volatile("s_waitcnt lgkmcnt(0)" ::: "memory");
          // A-side: rows of E (row-major read), hi for q<2 else lo
          float4 a0 = *(const float4*)(Er_p + nn * PB_STR + b8);
          float4 a1 = *(const float4*)(Er_p + nn * PB_STR + b8 + 4);
          float xa[8] = {a0.x, a0.y, a0.z, a0.w, a1.x, a1.y, a1.z, a1.w};
          v8h ahi, alo;
          split8(xa, ahi, alo);
          v8h Ecat = (q < 2) ? ahi : alo;
          // B-side: cols of E from Pt
          float4 r0 = *(const float4*)(Pt_p + nn * PB_STR + b8);
          float4 r1 = *(const float4*)(Pt_p + nn * PB_STR + b8 + 4);
          float xb[8] = {r0.x, r0.y, r0.z, r0.w, r1.x, r1.y, r1.z, r1.w};
          v8h fh, fl;
          split8(xb, fh, fl);
          v4f z = {0.f, 0.f, 0.f, 0.f};
          v4f c4 = __builtin_amdgcn_mfma_f32_16x16x32_f16(Ecat, fl, z, 0, 0, 0);
          c4 = __builtin_amdgcn_mfma_f32_16x16x32_f16(Ecat, fh, c4, 0, 0, 0);
          E[j] = c4;
        }
      }
    }

    // store T (C-layout regs -> row-major [16][16])
    #pragma unroll
    for (int j = 0; j < 2; ++j) {
      size_t p = (size_t)(base + 2 * cc + j);
      #pragma unroll
      for (int reg = 0; reg < 4; ++reg)
        Tg[p * 256 + (4 * q + reg) * 16 + nn] = E[j][reg];
    }
  }
}

// ---------------------------------------------------------------------------
// K5: settled[b,j] = sum_i attn[b,j,i] * (T[b,j,i] @ xm[b,i]);
//     out = settled @ Wo^T + bo
// ---------------------------------------------------------------------------
__global__ __launch_bounds__(256) void settle_kernel(
    const float* __restrict__ Tg, const float* __restrict__ attn,
    const float* __restrict__ xm, const float* __restrict__ Wo,
    const float* __restrict__ bo, float* __restrict__ outp) {
  int bj = blockIdx.x, b = bj >> 7;
  int t = threadIdx.x, lane = t & 63;
  int wu = __builtin_amdgcn_readfirstlane(t >> 6);
  int r = lane >> 2, a = lane & 3;
  float pacc = 0.f;
  for (int ii = 0; ii < 32; ++ii) {
    int i = wu * 32 + ii;
    size_t p = (size_t)bj * 128 + i;
    const float4 tv = *(const float4*)(Tg + (p << 8) + lane * 4);
    const float* xv = xm + (b * 128 + i) * 16;
    float aw = attn[p];
    float y = tv.x * xv[4 * a] + tv.y * xv[4 * a + 1] +
              tv.z * xv[4 * a + 2] + tv.w * xv[4 * a + 3];
    y += __shfl_xor(y, 1, 64);
    y += __shfl_xor(y, 2, 64);
    pacc = fmaf(aw, y, pacc);
  }
  __shared__ float sred[4][16];
  __shared__ float sfin[16];
  if (a == 0) sred[wu][r] = pacc;
  __syncthreads();
  if (t < 16) sfin[t] = sred[0][t] + sred[1][t] + sred[2][t] + sred[3][t];
  __syncthreads();
  if (t < 16) {
    float o = bo[t];
    const float* wr = Wo + t * 16;
    #pragma unroll
    for (int c = 0; c < 16; c++) o = fmaf(wr[c], sfin[c], o);
    outp[bj * 16 + t] = o;
  }
}

// ---------------------------------------------------------------------------
extern "C" void kernel_launch(void* const* d_in, const int* in_sizes, int n_in,
                              void* d_out, int out_size, void* d_ws,
                              size_t ws_size, hipStream_t stream) {
  const float* xl = (const float*)d_in[0];
  const float* xm = (const float*)d_in[1];
  const float* Wq = (const float*)d_in[2];
  const float* bq = (const float*)d_in[3];
  const float* Wk = (const float*)d_in[4];
  const float* bk = (const float*)d_in[5];
  const float* W1 = (const float*)d_in[6];
  const float* b1 = (const float*)d_in[7];
  const float* W2 = (const float*)d_in[8];
  const float* b2 = (const float*)d_in[9];
  const float* Wo = (const float*)d_in[10];
  const float* bo = (const float*)d_in[11];
  float* outp = (float*)d_out;
  float* Tg = outp + 8192;  // [65536][256] region: holds h, then T_all
  float* wsf = (float*)d_ws;
  float* Q = wsf;
  float* K = wsf + 65536;
  float* attn = wsf + 131072;  // 768 KB of ws used

  hipLaunchKernelGGL(qk_kernel, dim3(512), dim3(128), 0, stream, xl, Wq, bq, Wk, bk, Q, K);
  hipLaunchKernelGGL(attn_kernel, dim3(512), dim3(128), 0, stream, Q, K, attn);
  hipLaunchKernelGGL(h_kernel, dim3(4096), dim3(256), 0, stream, xl, W1, b1, Tg);
  hipLaunchKernelGGL(expm_kernel, dim3(1024), dim3(256), 0, stream, W2, b2, Tg);
  hipLaunchKernelGGL(settle_kernel, dim3(512), dim3(256), 0, stream, Tg, attn, xm, Wo, bo, outp);
}

// Round 4
// 247.933 us; speedup vs baseline: 1.6781x; 1.3695x over previous
//
#include <hip/hip_runtime.h>
#include <hip/hip_fp16.h>

// Problem constants
#define S_LEN 128
#define DLOG  128
#define DMEM  16
#define SO    120
#define HDIM  256

typedef _Float16 v8h __attribute__((ext_vector_type(8)));
typedef __fp16 v2hf __attribute__((ext_vector_type(2)));
typedef float v4f __attribute__((ext_vector_type(4)));

union PkU { v2hf h; unsigned u; };

// ---------------------------------------------------------------------------
// K1: Q = x@Wq^T + bq,  K = x@Wk^T + bk   (tiny)
// ---------------------------------------------------------------------------
__global__ __launch_bounds__(128) void qk_kernel(
    const float* __restrict__ xl, const float* __restrict__ Wq,
    const float* __restrict__ bq, const float* __restrict__ Wk,
    const float* __restrict__ bk, float* __restrict__ Q, float* __restrict__ K) {
  int bj = blockIdx.x, o = threadIdx.x;
  __shared__ float xs[128];
  xs[o] = xl[bj * 128 + o];
  __syncthreads();
  float aq = bq[o], ak = bk[o];
  const float* wq = Wq + o * 128;
  const float* wk = Wk + o * 128;
  #pragma unroll 4
  for (int d = 0; d < 128; ++d) {
    float x = xs[d];
    aq = fmaf(x, wq[d], aq);
    ak = fmaf(x, wk[d], ak);
  }
  Q[bj * 128 + o] = aq;
  K[bj * 128 + o] = ak;
}

// ---------------------------------------------------------------------------
// K2: attn[b,j,i] = softmax_i( Q[b,j].K[b,i] / sqrt(128) )
// ---------------------------------------------------------------------------
__global__ __launch_bounds__(128) void attn_kernel(
    const float* __restrict__ Q, const float* __restrict__ K,
    float* __restrict__ attn) {
  int bj = blockIdx.x, b = bj >> 7, i = threadIdx.x;
  __shared__ float qs[128];
  __shared__ float red[128];
  qs[i] = Q[bj * 128 + i];
  __syncthreads();
  const float* kr = K + (b * 128 + i) * 128;
  float s = 0.f;
  #pragma unroll 4
  for (int d = 0; d < 128; ++d) s = fmaf(qs[d], kr[d], s);
  s *= 0.08838834764831845f;  // 1/sqrt(128)
  red[i] = s;
  __syncthreads();
  for (int off = 64; off; off >>= 1) {
    if (i < off) red[i] = fmaxf(red[i], red[i + off]);
    __syncthreads();
  }
  float m = red[0];
  __syncthreads();
  float e = expf(s - m);
  red[i] = e;
  __syncthreads();
  for (int off = 64; off; off >>= 1) {
    if (i < off) red[i] += red[i + off];
    __syncthreads();
  }
  attn[(size_t)bj * 128 + i] = e / red[0];
}

// ---------------------------------------------------------------------------
// K3 (MFMA): h[p][o] = tanh(delta[p].W1[o] + b1[o]), stored f16 in the first
// 512 B of pair p's 1024-B T-slot (same-pair overwrite later -> race-free).
// Block = (bj, o-half): stages W1-half [128][136]f16 once, delta in 2 passes
// of 64 i-rows to stay under 64 KB static LDS (52736 B -> 3 blocks/CU).
// ---------------------------------------------------------------------------
__global__ __launch_bounds__(256) void h_kernel(
    const float* __restrict__ xl, const float* __restrict__ W1,
    const float* __restrict__ b1, __half* __restrict__ hG) {
  __shared__ _Float16 w1s[128 * 136];
  __shared__ _Float16 dstage[64 * 136];
  __shared__ float xjs[128];
  int t = threadIdx.x;
  int blk = blockIdx.x;
  int bj = blk >> 1;   // 0..511
  int oh = blk & 1;    // o-half
  int b = bj >> 7;
  int o0 = oh * 128;

  if (t < 128) xjs[t] = xl[bj * 128 + t];
  for (int idx = t; idx < 128 * 128; idx += 256) {
    int o = idx >> 7, k = idx & 127;
    w1s[o * 136 + k] = (_Float16)W1[(o0 + o) * 128 + k];
  }
  __syncthreads();

  int lane = t & 63, w = t >> 6;
  int nn = lane & 15, q = lane >> 4;
  int ow = o0 + w * 32;
  float bb0 = b1[ow + nn], bb1 = b1[ow + 16 + nn];
  const float* xb = xl + (size_t)b * 128 * 128;

  for (int pi = 0; pi < 2; ++pi) {
    // stage delta f16 for i in [pi*64, pi*64+64)
    for (int idx = t; idx < 64 * 128; idx += 256) {
      int i = idx >> 7, k = idx & 127;
      dstage[i * 136 + k] = (_Float16)(xjs[k] - xb[(pi * 64 + i) * 128 + k]);
    }
    __syncthreads();

    v4f acc[4][2];
    #pragma unroll
    for (int mi = 0; mi < 4; ++mi) {
      acc[mi][0] = (v4f){0.f, 0.f, 0.f, 0.f};
      acc[mi][1] = (v4f){0.f, 0.f, 0.f, 0.f};
    }
    #pragma unroll
    for (int ks = 0; ks < 4; ++ks) {
      v8h bf0 = *(const v8h*)&w1s[(w * 32 + nn) * 136 + ks * 32 + q * 8];
      v8h bf1 = *(const v8h*)&w1s[(w * 32 + 16 + nn) * 136 + ks * 32 + q * 8];
      #pragma unroll
      for (int mi = 0; mi < 4; ++mi) {
        v8h af = *(const v8h*)&dstage[(mi * 16 + nn) * 136 + ks * 32 + q * 8];
        acc[mi][0] = __builtin_amdgcn_mfma_f32_16x16x32_f16(af, bf0, acc[mi][0], 0, 0, 0);
        acc[mi][1] = __builtin_amdgcn_mfma_f32_16x16x32_f16(af, bf1, acc[mi][1], 0, 0, 0);
      }
    }
    // epilogue: tanh + f16 store
    #pragma unroll
    for (int mi = 0; mi < 4; ++mi) {
      #pragma unroll
      for (int nt = 0; nt < 2; ++nt) {
        int o = ow + nt * 16 + nn;
        float bbv = nt ? bb1 : bb0;
        #pragma unroll
        for (int reg = 0; reg < 4; ++reg) {
          int i = pi * 64 + mi * 16 + 4 * q + reg;
          float x = acc[mi][nt][reg] + bbv;
          float ax = fabsf(x);
          float e = __expf(-2.f * ax);
          float r = __fdividef(1.f - e, 1.f + e);
          r = copysignf(r, x);
          hG[(size_t)(bj * 128 + i) * 512 + o] = __float2half(r);
        }
      }
    }
    __syncthreads();  // before pass 2 restages dstage
  }
}

// ---------------------------------------------------------------------------
// K4: lie = h@W2^T + b2 (f16 MFMA, h read f16 from slot); per-pair
// T = expm(skew): A-side exact via K-concat [Ahi|Alo], B-side f16-dup [P;P]
// -> single MFMA per matmul. P/E-col f16 col-major [16 col][16 row] in LDS.
// ---------------------------------------------------------------------------
#define WAVE_LDS 7936  // 4352 lieb f16 + 1024 Pt f16 x2 + 2560 Er f32 x2

__device__ __forceinline__ void split8(const float* x, v8h& hi, v8h& lo) {
  union U { v8h v; v2hf p[4]; } H, L;
  #pragma unroll
  for (int i = 0; i < 4; ++i) {
    float a = x[2 * i], b = x[2 * i + 1];
    v2hf h = __builtin_amdgcn_cvt_pkrtz(a, b);
    float ra = (float)h[0], rb = (float)h[1];
    v2hf l = __builtin_amdgcn_cvt_pkrtz(a - ra, b - rb);
    H.p[i] = h;
    L.p[i] = l;
  }
  hi = H.v;
  lo = L.v;
}

__device__ __forceinline__ int lie_idx(int rr, int cc) {
  return 15 * rr - ((rr * (rr - 1)) >> 1) + cc - rr - 1;
}

__global__ __launch_bounds__(256) void expm_kernel(
    const float* __restrict__ W2g, const float* __restrict__ b2g,
    float* __restrict__ Tg) {
  __shared__ char ldsraw[34816] __attribute__((aligned(16)));
  _Float16* w2t = (_Float16*)ldsraw;  // [128 n][136 k] f16, phase A only

  int t = threadIdx.x, lane = t & 63;
  int wu = __builtin_amdgcn_readfirstlane(t >> 6);
  int base = (blockIdx.x * 4 + wu) * 16;  // 16 pairs per wave
  const int nn = lane & 15;
  const int q = lane >> 4;
  const int b8 = (q & 1) * 8;

  char* wb = ldsraw + (size_t)wu * WAVE_LDS;
  _Float16* lieb = (_Float16*)wb;             // [16 pair][136] f16
  _Float16* PtB = (_Float16*)(wb + 4352);     // 2 x [16 col][16 row] f16
  float* ErB = (float*)(wb + 5376);           // 2 x [16 row][20] f32

  // ================= phase A: lie GEMM (h f16 from global) =================
  v4f acc[8];
  #pragma unroll
  for (int tt = 0; tt < 8; ++tt) acc[tt] = (v4f){0.f, 0.f, 0.f, 0.f};

  const __half* hGc = (const __half*)Tg;
  const __half* hrow = hGc + (size_t)(base + nn) * 512;
  for (int khalf = 0; khalf < 2; ++khalf) {
    __syncthreads();
    for (int idx = t; idx < 120 * 128; idx += 256) {
      int o = idx >> 7, kk = idx & 127;
      w2t[o * 136 + kk] = (_Float16)W2g[o * 256 + khalf * 128 + kk];
    }
    for (int idx = t; idx < 8 * 128; idx += 256)
      w2t[(120 + (idx >> 7)) * 136 + (idx & 127)] = (_Float16)0.f;
    __syncthreads();
    #pragma unroll
    for (int ks = 0; ks < 4; ++ks) {
      v8h ah = *(const v8h*)(hrow + khalf * 128 + ks * 32 + 8 * q);
      #pragma unroll
      for (int tt = 0; tt < 8; ++tt) {
        const v8h bf = *(const v8h*)(w2t + (16 * tt + nn) * 136 + ks * 32 + 8 * q);
        acc[tt] = __builtin_amdgcn_mfma_f32_16x16x32_f16(ah, bf, acc[tt], 0, 0, 0);
      }
    }
  }
  __syncthreads();  // all waves done with w2t before lieb overwrites it

  // bias + scatter lie (f16) to per-wave LDS
  #pragma unroll
  for (int tt = 0; tt < 8; ++tt) {
    int n16 = 16 * tt + nn;
    float bb = (n16 < 120) ? b2g[n16] : 0.f;
    #pragma unroll
    for (int reg = 0; reg < 4; ++reg) {
      int pr = 4 * q + reg;
      float v = (n16 < 120) ? (acc[tt][reg] + bb) : 0.f;
      lieb[pr * 136 + n16] = (_Float16)v;
    }
  }
  asm volatile("s_waitcnt lgkmcnt(0)" ::: "memory");

  // ================= phase B: per-pair expm =================
  for (int cc = 0; cc < 8; ++cc) {
    int sA[2];
    v8h Acat[2];
    v4f E[2];
    #pragma unroll
    for (int j = 0; j < 2; ++j) {
      int p = 2 * cc + j;
      const _Float16* lp = lieb + p * 136;
      float v0 = (float)lp[lane], v1 = (float)lp[lane + 64];
      float s2 = v0 * v0 + v1 * v1;
      #pragma unroll
      for (int off = 1; off < 64; off <<= 1) s2 += __shfl_xor(s2, off, 64);
      float bound = sqrtf(s2);  // ||A||_2 <= sqrt(sum lie^2) for skew
      int s = 0;
      while (bound > 1.0f && s < 12) { bound *= 0.5f; s++; }
      sA[j] = s;
      float sc = ldexpf(1.0f, -s);

      // A-operand frag (exact): q<2 -> Ahi cols b8.., q>=2 -> Alo
      float av[8];
      #pragma unroll
      for (int jj = 0; jj < 8; ++jj) {
        int c = b8 + jj;
        int rr = min(nn, c), c2 = max(nn, c);
        int li = (c == nn) ? 0 : lie_idx(rr, c2);
        float lv = (float)lp[li];
        av[jj] = (c == nn) ? 0.f : ((c > nn) ? lv : -lv) * sc;
      }
      v8h hi, lo;
      split8(av, hi, lo);
      Acat[j] = (q < 2) ? hi : lo;

      // E = I + A (C-layout);  P1 = A -> Pt f16 col-major
      float Pw[4], e4[4];
      #pragma unroll
      for (int reg = 0; reg < 4; ++reg) {
        int r = 4 * q + reg, c = nn;
        int rr = min(r, c), c2 = max(r, c);
        int li = (r == c) ? 0 : lie_idx(rr, c2);
        float lv = (float)lp[li];
        float v = (r == c) ? 0.f : ((c > r) ? lv : -lv) * sc;
        Pw[reg] = v;
        e4[reg] = v + ((r == c) ? 1.f : 0.f);
      }
      _Float16* Ptp = PtB + j * 256;
      PkU u0, u1;
      u0.h = __builtin_amdgcn_cvt_pkrtz(Pw[0], Pw[1]);
      u1.h = __builtin_amdgcn_cvt_pkrtz(Pw[2], Pw[3]);
      *(uint2*)(Ptp + nn * 16 + 4 * q) = make_uint2(u0.u, u1.u);
      E[j] = (v4f){e4[0], e4[1], e4[2], e4[3]};
    }
    asm volatile("s_waitcnt lgkmcnt(0)" ::: "memory");

    // Taylor terms k=2..9: single MFMA each (A exact, B=[P;P] f16)
    #pragma unroll
    for (int k = 2; k <= 9; ++k) {
      const float rk = 1.0f / (float)k;
      #pragma unroll
      for (int j = 0; j < 2; ++j) {
        _Float16* Ptp = PtB + j * 256;
        v8h bf = *(const v8h*)(Ptp + nn * 16 + b8);
        v4f z = {0.f, 0.f, 0.f, 0.f};
        v4f c4 = __builtin_amdgcn_mfma_f32_16x16x32_f16(Acat[j], bf, z, 0, 0, 0);
        c4 = c4 * rk;  // P_k
        E[j] += c4;
        PkU u0, u1;
        u0.h = __builtin_amdgcn_cvt_pkrtz(c4[0], c4[1]);
        u1.h = __builtin_amdgcn_cvt_pkrtz(c4[2], c4[3]);
        *(uint2*)(Ptp + nn * 16 + 4 * q) = make_uint2(u0.u, u1.u);
      }
      asm volatile("s_waitcnt lgkmcnt(0)" ::: "memory");
    }

    // squarings: E <- E*E, A-side exact (Er f32 rows), B-side f16 cols
    int smax = max(sA[0], sA[1]);
    for (int it = 0; it < smax; ++it) {
      #pragma unroll
      for (int j = 0; j < 2; ++j) {
        if (it < sA[j]) {
          _Float16* Ptp = PtB + j * 256;
          float* Erp = ErB + j * 320;
          #pragma unroll
          for (int reg = 0; reg < 4; ++reg)
            Erp[(4 * q + reg) * 20 + nn] = E[j][reg];
          PkU u0, u1;
          u0.h = __builtin_amdgcn_cvt_pkrtz(E[j][0], E[j][1]);
          u1.h = __builtin_amdgcn_cvt_pkrtz(E[j][2], E[j][3]);
          *(uint2*)(Ptp + nn * 16 + 4 * q) = make_uint2(u0.u, u1.u);
          asm volatile("s_waitcnt lgkmcnt(0)" ::: "memory");
          float4 a0 = *(const float4*)(Erp + nn * 20 + b8);
          float4 a1 = *(const float4*)(Erp + nn * 20 + b8 + 4);
          float xa[8] = {a0.x, a0.y, a0.z, a0.w, a1.x, a1.y, a1.z, a1.w};
          v8h ahi, alo;
          split8(xa, ahi, alo);
          v8h Ecat = (q < 2) ? ahi : alo;
          v8h bf = *(const v8h*)(Ptp + nn * 16 + b8);
          v4f z = {0.f, 0.f, 0.f, 0.f};
          E[j] = __builtin_amdgcn_mfma_f32_16x16x32_f16(Ecat, bf, z, 0, 0, 0);
        }
      }
    }

    // store T (C-layout regs -> row-major [16][16] fp32)
    #pragma unroll
    for (int j = 0; j < 2; ++j) {
      size_t p = (size_t)(base + 2 * cc + j);
      #pragma unroll
      for (int reg = 0; reg < 4; ++reg)
        Tg[p * 256 + (4 * q + reg) * 16 + nn] = E[j][reg];
    }
  }
}

// ---------------------------------------------------------------------------
// K5: settled[b,j] = sum_i attn[b,j,i] * (T[b,j,i] @ xm[b,i]);
//     out = settled @ Wo^T + bo
// ---------------------------------------------------------------------------
__global__ __launch_bounds__(256) void settle_kernel(
    const float* __restrict__ Tg, const float* __restrict__ attn,
    const float* __restrict__ xm, const float* __restrict__ Wo,
    const float* __restrict__ bo, float* __restrict__ outp) {
  int bj = blockIdx.x, b = bj >> 7;
  int t = threadIdx.x, lane = t & 63;
  int wu = __builtin_amdgcn_readfirstlane(t >> 6);
  int r = lane >> 2, a = lane & 3;
  float pacc = 0.f;
  for (int ii = 0; ii < 32; ++ii) {
    int i = wu * 32 + ii;
    size_t p = (size_t)bj * 128 + i;
    const float4 tv = *(const float4*)(Tg + (p << 8) + lane * 4);
    const float* xv = xm + (b * 128 + i) * 16;
    float aw = attn[p];
    float y = tv.x * xv[4 * a] + tv.y * xv[4 * a + 1] +
              tv.z * xv[4 * a + 2] + tv.w * xv[4 * a + 3];
    y += __shfl_xor(y, 1, 64);
    y += __shfl_xor(y, 2, 64);
    pacc = fmaf(aw, y, pacc);
  }
  __shared__ float sred[4][16];
  __shared__ float sfin[16];
  if (a == 0) sred[wu][r] = pacc;
  __syncthreads();
  if (t < 16) sfin[t] = sred[0][t] + sred[1][t] + sred[2][t] + sred[3][t];
  __syncthreads();
  if (t < 16) {
    float o = bo[t];
    const float* wr = Wo + t * 16;
    #pragma unroll
    for (int c = 0; c < 16; c++) o = fmaf(wr[c], sfin[c], o);
    outp[bj * 16 + t] = o;
  }
}

// ---------------------------------------------------------------------------
extern "C" void kernel_launch(void* const* d_in, const int* in_sizes, int n_in,
                              void* d_out, int out_size, void* d_ws,
                              size_t ws_size, hipStream_t stream) {
  const float* xl = (const float*)d_in[0];
  const float* xm = (const float*)d_in[1];
  const float* Wq = (const float*)d_in[2];
  const float* bq = (const float*)d_in[3];
  const float* Wk = (const float*)d_in[4];
  const float* bk = (const float*)d_in[5];
  const float* W1 = (const float*)d_in[6];
  const float* b1 = (const float*)d_in[7];
  const float* W2 = (const float*)d_in[8];
  const float* b2 = (const float*)d_in[9];
  const float* Wo = (const float*)d_in[10];
  const float* bo = (const float*)d_in[11];
  float* outp = (float*)d_out;
  float* Tg = outp + 8192;  // [65536][256] region: h (f16, slot-local), then T
  float* wsf = (float*)d_ws;
  float* Q = wsf;
  float* K = wsf + 65536;
  float* attn = wsf + 131072;  // 768 KB of ws used

  hipLaunchKernelGGL(qk_kernel, dim3(512), dim3(128), 0, stream, xl, Wq, bq, Wk, bk, Q, K);
  hipLaunchKernelGGL(attn_kernel, dim3(512), dim3(128), 0, stream, Q, K, attn);
  hipLaunchKernelGGL(h_kernel, dim3(1024), dim3(256), 0, stream, xl, W1, b1, (__half*)Tg);
  hipLaunchKernelGGL(expm_kernel, dim3(1024), dim3(256), 0, stream, W2, b2, Tg);
  hipLaunchKernelGGL(settle_kernel, dim3(512), dim3(256), 0, stream, Tg, attn, xm, Wo, bo, outp);
}

// Round 5
// 220.232 us; speedup vs baseline: 1.8892x; 1.1258x over previous
//
#include <hip/hip_runtime.h>
#include <hip/hip_fp16.h>

// Problem constants
#define S_LEN 128
#define DLOG  128
#define DMEM  16
#define SO    120
#define HDIM  256

typedef _Float16 v8h __attribute__((ext_vector_type(8)));
typedef __fp16 v2hf __attribute__((ext_vector_type(2)));
typedef float v4f __attribute__((ext_vector_type(4)));

union PkU { v2hf h; unsigned u; };
union V8U { v8h v; int u[4]; };

// ---------------------------------------------------------------------------
// K1: Q = x@Wq^T + bq,  K = x@Wk^T + bk   (tiny)
// ---------------------------------------------------------------------------
__global__ __launch_bounds__(128) void qk_kernel(
    const float* __restrict__ xl, const float* __restrict__ Wq,
    const float* __restrict__ bq, const float* __restrict__ Wk,
    const float* __restrict__ bk, float* __restrict__ Q, float* __restrict__ K) {
  int bj = blockIdx.x, o = threadIdx.x;
  __shared__ float xs[128];
  xs[o] = xl[bj * 128 + o];
  __syncthreads();
  float aq = bq[o], ak = bk[o];
  const float* wq = Wq + o * 128;
  const float* wk = Wk + o * 128;
  #pragma unroll 4
  for (int d = 0; d < 128; ++d) {
    float x = xs[d];
    aq = fmaf(x, wq[d], aq);
    ak = fmaf(x, wk[d], ak);
  }
  Q[bj * 128 + o] = aq;
  K[bj * 128 + o] = ak;
}

// ---------------------------------------------------------------------------
// K2: attn[b,j,i] = softmax_i( Q[b,j].K[b,i] / sqrt(128) )
// ---------------------------------------------------------------------------
__global__ __launch_bounds__(128) void attn_kernel(
    const float* __restrict__ Q, const float* __restrict__ K,
    float* __restrict__ attn) {
  int bj = blockIdx.x, b = bj >> 7, i = threadIdx.x;
  __shared__ float qs[128];
  __shared__ float red[128];
  qs[i] = Q[bj * 128 + i];
  __syncthreads();
  const float* kr = K + (b * 128 + i) * 128;
  float s = 0.f;
  #pragma unroll 4
  for (int d = 0; d < 128; ++d) s = fmaf(qs[d], kr[d], s);
  s *= 0.08838834764831845f;  // 1/sqrt(128)
  red[i] = s;
  __syncthreads();
  for (int off = 64; off; off >>= 1) {
    if (i < off) red[i] = fmaxf(red[i], red[i + off]);
    __syncthreads();
  }
  float m = red[0];
  __syncthreads();
  float e = expf(s - m);
  red[i] = e;
  __syncthreads();
  for (int off = 64; off; off >>= 1) {
    if (i < off) red[i] += red[i + off];
    __syncthreads();
  }
  attn[(size_t)bj * 128 + i] = e / red[0];
}

// ---------------------------------------------------------------------------
// K3 (MFMA): h[p][o] = tanh(delta[p].W1[o] + b1[o]), stored f16 in the first
// 512 B of pair p's 1024-B T-slot.
// ---------------------------------------------------------------------------
__global__ __launch_bounds__(256) void h_kernel(
    const float* __restrict__ xl, const float* __restrict__ W1,
    const float* __restrict__ b1, __half* __restrict__ hG) {
  __shared__ _Float16 w1s[128 * 136];
  __shared__ _Float16 dstage[64 * 136];
  __shared__ float xjs[128];
  int t = threadIdx.x;
  int blk = blockIdx.x;
  int bj = blk >> 1;   // 0..511
  int oh = blk & 1;    // o-half
  int b = bj >> 7;
  int o0 = oh * 128;

  if (t < 128) xjs[t] = xl[bj * 128 + t];
  for (int idx = t; idx < 128 * 128; idx += 256) {
    int o = idx >> 7, k = idx & 127;
    w1s[o * 136 + k] = (_Float16)W1[(o0 + o) * 128 + k];
  }
  __syncthreads();

  int lane = t & 63, w = t >> 6;
  int nn = lane & 15, q = lane >> 4;
  int ow = o0 + w * 32;
  float bb0 = b1[ow + nn], bb1 = b1[ow + 16 + nn];
  const float* xb = xl + (size_t)b * 128 * 128;

  for (int pi = 0; pi < 2; ++pi) {
    for (int idx = t; idx < 64 * 128; idx += 256) {
      int i = idx >> 7, k = idx & 127;
      dstage[i * 136 + k] = (_Float16)(xjs[k] - xb[(pi * 64 + i) * 128 + k]);
    }
    __syncthreads();

    v4f acc[4][2];
    #pragma unroll
    for (int mi = 0; mi < 4; ++mi) {
      acc[mi][0] = (v4f){0.f, 0.f, 0.f, 0.f};
      acc[mi][1] = (v4f){0.f, 0.f, 0.f, 0.f};
    }
    #pragma unroll
    for (int ks = 0; ks < 4; ++ks) {
      v8h bf0 = *(const v8h*)&w1s[(w * 32 + nn) * 136 + ks * 32 + q * 8];
      v8h bf1 = *(const v8h*)&w1s[(w * 32 + 16 + nn) * 136 + ks * 32 + q * 8];
      #pragma unroll
      for (int mi = 0; mi < 4; ++mi) {
        v8h af = *(const v8h*)&dstage[(mi * 16 + nn) * 136 + ks * 32 + q * 8];
        acc[mi][0] = __builtin_amdgcn_mfma_f32_16x16x32_f16(af, bf0, acc[mi][0], 0, 0, 0);
        acc[mi][1] = __builtin_amdgcn_mfma_f32_16x16x32_f16(af, bf1, acc[mi][1], 0, 0, 0);
      }
    }
    #pragma unroll
    for (int mi = 0; mi < 4; ++mi) {
      #pragma unroll
      for (int nt = 0; nt < 2; ++nt) {
        int o = ow + nt * 16 + nn;
        float bbv = nt ? bb1 : bb0;
        #pragma unroll
        for (int reg = 0; reg < 4; ++reg) {
          int i = pi * 64 + mi * 16 + 4 * q + reg;
          float x = acc[mi][nt][reg] + bbv;
          float ax = fabsf(x);
          float e = __expf(-2.f * ax);
          float r = __fdividef(1.f - e, 1.f + e);
          r = copysignf(r, x);
          hG[(size_t)(bj * 128 + i) * 512 + o] = __float2half(r);
        }
      }
    }
    __syncthreads();
  }
}

// ---------------------------------------------------------------------------
// K4a: lie[p][n] = h[p] . W2[n] + b2[n], f16 MFMA GEMM (M=pairs, N=120pad128,
// K=256). h read f16 from slot bytes [0,512); lie written f16 to slot bytes
// [512,752). 64 pairs/block, W2 staged in two K-halves.
// ---------------------------------------------------------------------------
__global__ __launch_bounds__(256) void lie_kernel(
    const float* __restrict__ W2g, const float* __restrict__ b2g,
    float* __restrict__ Tg) {
  __shared__ _Float16 w2t[128 * 136];
  int t = threadIdx.x, lane = t & 63;
  int wu = __builtin_amdgcn_readfirstlane(t >> 6);
  int pbase = blockIdx.x * 64 + wu * 16;
  int nn = lane & 15, q = lane >> 4;
  const _Float16* hf = (const _Float16*)Tg;

  v4f acc[8];
  #pragma unroll
  for (int tt = 0; tt < 8; ++tt) acc[tt] = (v4f){0.f, 0.f, 0.f, 0.f};

  const _Float16* hrow = hf + (size_t)(pbase + nn) * 512;
  for (int khalf = 0; khalf < 2; ++khalf) {
    __syncthreads();
    for (int idx = t; idx < 120 * 128; idx += 256) {
      int o = idx >> 7, kk = idx & 127;
      w2t[o * 136 + kk] = (_Float16)W2g[o * 256 + khalf * 128 + kk];
    }
    for (int idx = t; idx < 8 * 128; idx += 256)
      w2t[(120 + (idx >> 7)) * 136 + (idx & 127)] = (_Float16)0.f;
    __syncthreads();
    #pragma unroll
    for (int ks = 0; ks < 4; ++ks) {
      v8h ah = *(const v8h*)(hrow + khalf * 128 + ks * 32 + 8 * q);
      #pragma unroll
      for (int tt = 0; tt < 8; ++tt) {
        const v8h bf = *(const v8h*)(w2t + (16 * tt + nn) * 136 + ks * 32 + 8 * q);
        acc[tt] = __builtin_amdgcn_mfma_f32_16x16x32_f16(ah, bf, acc[tt], 0, 0, 0);
      }
    }
  }

  _Float16* hw = (_Float16*)Tg;
  #pragma unroll
  for (int tt = 0; tt < 8; ++tt) {
    int n16 = 16 * tt + nn;
    if (n16 < 120) {
      float bb = b2g[n16];
      #pragma unroll
      for (int reg = 0; reg < 4; ++reg) {
        size_t p = (size_t)(pbase + 4 * q + reg);
        hw[p * 512 + 256 + n16] = (_Float16)(acc[tt][reg] + bb);
      }
    }
  }
}

// ---------------------------------------------------------------------------
// K4b: per-pair T = expm(skew(lie)). 2 pairs/wave, waves fully independent
// (no __syncthreads). A = scaled skew is f16-EXACT (lie stored f16, pow2
// scale) -> [A|A]*[P;P] = 2AP in ONE MFMA. C->B layout transform via
// ds_bpermute (register dataflow, no LDS). Squarings (rare, s~2) keep the
// exact [Ehi|Elo] A-side via a small per-wave LDS transpose buffer.
// ---------------------------------------------------------------------------
__device__ __forceinline__ void split8(const float* x, v8h& hi, v8h& lo) {
  union U { v8h v; v2hf p[4]; } H, L;
  #pragma unroll
  for (int i = 0; i < 4; ++i) {
    float a = x[2 * i], b = x[2 * i + 1];
    v2hf h = __builtin_amdgcn_cvt_pkrtz(a, b);
    float ra = (float)h[0], rb = (float)h[1];
    v2hf l = __builtin_amdgcn_cvt_pkrtz(a - ra, b - rb);
    H.p[i] = h;
    L.p[i] = l;
  }
  hi = H.v;
  lo = L.v;
}

__device__ __forceinline__ int lie_idx(int rr, int cc) {
  return 15 * rr - ((rr * (rr - 1)) >> 1) + cc - rr - 1;
}

__global__ __launch_bounds__(256) void expm_kernel(float* __restrict__ Tg) {
  __shared__ char lds[12288] __attribute__((aligned(16)));
  int t = threadIdx.x, lane = t & 63;
  int wu = __builtin_amdgcn_readfirstlane(t >> 6);
  int pbase = blockIdx.x * 8 + wu * 2;
  int nn = lane & 15, q = lane >> 4, b8 = (q & 1) * 8;
  char* wb = lds + wu * 3072;
  _Float16* lieS = (_Float16*)wb;   // [2][128] f16
  float* ErB = (float*)(wb + 512);  // [2][320] f32 (16 rows x stride 20)
  const _Float16* hf = (const _Float16*)Tg;

  // bpermute source lanes for the C-layout -> B-layout transform:
  // requester (q,nn) needs regs of lanes 16*(2*(q&1))+nn and +16.
  int idxA = ((2 * (q & 1)) * 16 + nn) * 4;
  int idxB = idxA + 64;

  // ---- load lie, compute per-pair scaling ----
  float scv[2];
  int sv[2];
  #pragma unroll
  for (int j = 0; j < 2; ++j) {
    size_t p = (size_t)(pbase + j);
    _Float16 a0 = (lane < 120) ? hf[p * 512 + 256 + lane] : (_Float16)0.f;
    _Float16 a1 = (lane < 56) ? hf[p * 512 + 320 + lane] : (_Float16)0.f;
    lieS[j * 128 + lane] = a0;
    lieS[j * 128 + 64 + lane] = a1;
    float f0 = (float)a0, f1 = (float)a1;
    float s2 = f0 * f0 + f1 * f1;
    #pragma unroll
    for (int off = 1; off < 64; off <<= 1) s2 += __shfl_xor(s2, off, 64);
    float bound = sqrtf(s2);  // ||A||_2 <= sqrt(sum lie^2) for skew
    int s = 0;
    while (bound > 1.0f && s < 12) { bound *= 0.5f; s++; }
    sv[j] = __builtin_amdgcn_readfirstlane(s);
    scv[j] = ldexpf(1.0f, -s);
  }
  asm volatile("s_waitcnt lgkmcnt(0)" ::: "memory");

  // ---- build A-frag (f16-exact), P1 B-frag (= -A rows), E = I + A ----
  V8U Apk[2], bf[2];
  v4f E[2];
  #pragma unroll
  for (int j = 0; j < 2; ++j) {
    const _Float16* lp = lieS + j * 128;
    float sc = scv[j];
    float av[8];
    #pragma unroll
    for (int jj = 0; jj < 8; ++jj) {
      int c = b8 + jj;
      int rr = min(nn, c), c2 = max(nn, c);
      float lv = (c == nn) ? 0.f : (float)lp[lie_idx(rr, c2)];
      av[jj] = (c == nn) ? 0.f : ((c > nn) ? lv : -lv) * sc;
    }
    #pragma unroll
    for (int i = 0; i < 4; ++i) {
      PkU u;
      u.h = __builtin_amdgcn_cvt_pkrtz(av[2 * i], av[2 * i + 1]);
      Apk[j].u[i] = (int)u.u;
    }
    // B-frag of P1: P1[k][n] = A[k][nn] = -A[nn][k]  -> negate packed f16
    #pragma unroll
    for (int i = 0; i < 4; ++i) bf[j].u[i] = Apk[j].u[i] ^ 0x80008000;
    // E = I + A in C-layout (rows 4q+reg, col nn)
    #pragma unroll
    for (int reg = 0; reg < 4; ++reg) {
      int r = 4 * q + reg;
      int rr = min(r, nn), c2 = max(r, nn);
      float lv = (r == nn) ? 0.f : (float)lp[lie_idx(rr, c2)];
      float v = (r == nn) ? 0.f : ((nn > r) ? lv : -lv) * sc;
      E[j][reg] = v + ((r == nn) ? 1.f : 0.f);
    }
  }

  // ---- Taylor terms k=2..9: one MFMA per term, bpermute transform ----
  #pragma unroll
  for (int k = 2; k <= 9; ++k) {
    const float rk = 1.0f / (2.0f * (float)k);  // 1/2 folds the [A|A] dup
    #pragma unroll
    for (int j = 0; j < 2; ++j) {
      v4f z = {0.f, 0.f, 0.f, 0.f};
      v4f c4 = __builtin_amdgcn_mfma_f32_16x16x32_f16(Apk[j].v, bf[j].v, z, 0, 0, 0);
      c4 = c4 * rk;  // P_k
      E[j] += c4;
      if (k < 9) {
        PkU u0, u1;
        u0.h = __builtin_amdgcn_cvt_pkrtz(c4[0], c4[1]);
        u1.h = __builtin_amdgcn_cvt_pkrtz(c4[2], c4[3]);
        bf[j].u[0] = __builtin_amdgcn_ds_bpermute(idxA, (int)u0.u);
        bf[j].u[1] = __builtin_amdgcn_ds_bpermute(idxA, (int)u1.u);
        bf[j].u[2] = __builtin_amdgcn_ds_bpermute(idxB, (int)u0.u);
        bf[j].u[3] = __builtin_amdgcn_ds_bpermute(idxB, (int)u1.u);
      }
    }
  }

  // ---- squarings: E <- E*E (A-side exact hi/lo via LDS row transpose) ----
  int smax = max(sv[0], sv[1]);
  for (int it = 0; it < smax; ++it) {
    #pragma unroll
    for (int j = 0; j < 2; ++j) {
      if (it < sv[j]) {
        float* Erp = ErB + j * 320;
        // B-side via bpermute of packed E
        PkU u0, u1;
        u0.h = __builtin_amdgcn_cvt_pkrtz(E[j][0], E[j][1]);
        u1.h = __builtin_amdgcn_cvt_pkrtz(E[j][2], E[j][3]);
        V8U bfe;
        bfe.u[0] = __builtin_amdgcn_ds_bpermute(idxA, (int)u0.u);
        bfe.u[1] = __builtin_amdgcn_ds_bpermute(idxA, (int)u1.u);
        bfe.u[2] = __builtin_amdgcn_ds_bpermute(idxB, (int)u0.u);
        bfe.u[3] = __builtin_amdgcn_ds_bpermute(idxB, (int)u1.u);
        // A-side: E rows via LDS
        #pragma unroll
        for (int reg = 0; reg < 4; ++reg)
          Erp[(4 * q + reg) * 20 + nn] = E[j][reg];
        asm volatile("s_waitcnt lgkmcnt(0)" ::: "memory");
        float4 a0 = *(const float4*)(Erp + nn * 20 + b8);
        float4 a1 = *(const float4*)(Erp + nn * 20 + b8 + 4);
        float xa[8] = {a0.x, a0.y, a0.z, a0.w, a1.x, a1.y, a1.z, a1.w};
        v8h ahi, alo;
        split8(xa, ahi, alo);
        v8h Ecat = (q < 2) ? ahi : alo;
        v4f z = {0.f, 0.f, 0.f, 0.f};
        E[j] = __builtin_amdgcn_mfma_f32_16x16x32_f16(Ecat, bfe.v, z, 0, 0, 0);
      }
    }
  }

  // ---- store T (C-layout -> row-major [16][16] fp32) ----
  #pragma unroll
  for (int j = 0; j < 2; ++j) {
    float* dst = Tg + (size_t)(pbase + j) * 256;
    #pragma unroll
    for (int reg = 0; reg < 4; ++reg)
      dst[(4 * q + reg) * 16 + nn] = E[j][reg];
  }
}

// ---------------------------------------------------------------------------
// K5: settled[b,j] = sum_i attn[b,j,i] * (T[b,j,i] @ xm[b,i]);
//     out = settled @ Wo^T + bo
// ---------------------------------------------------------------------------
__global__ __launch_bounds__(256) void settle_kernel(
    const float* __restrict__ Tg, const float* __restrict__ attn,
    const float* __restrict__ xm, const float* __restrict__ Wo,
    const float* __restrict__ bo, float* __restrict__ outp) {
  int bj = blockIdx.x, b = bj >> 7;
  int t = threadIdx.x, lane = t & 63;
  int wu = __builtin_amdgcn_readfirstlane(t >> 6);
  int r = lane >> 2, a = lane & 3;
  float pacc = 0.f;
  for (int ii = 0; ii < 32; ++ii) {
    int i = wu * 32 + ii;
    size_t p = (size_t)bj * 128 + i;
    const float4 tv = *(const float4*)(Tg + (p << 8) + lane * 4);
    const float* xv = xm + (b * 128 + i) * 16;
    float aw = attn[p];
    float y = tv.x * xv[4 * a] + tv.y * xv[4 * a + 1] +
              tv.z * xv[4 * a + 2] + tv.w * xv[4 * a + 3];
    y += __shfl_xor(y, 1, 64);
    y += __shfl_xor(y, 2, 64);
    pacc = fmaf(aw, y, pacc);
  }
  __shared__ float sred[4][16];
  __shared__ float sfin[16];
  if (a == 0) sred[wu][r] = pacc;
  __syncthreads();
  if (t < 16) sfin[t] = sred[0][t] + sred[1][t] + sred[2][t] + sred[3][t];
  __syncthreads();
  if (t < 16) {
    float o = bo[t];
    const float* wr = Wo + t * 16;
    #pragma unroll
    for (int c = 0; c < 16; c++) o = fmaf(wr[c], sfin[c], o);
    outp[bj * 16 + t] = o;
  }
}

// ---------------------------------------------------------------------------
extern "C" void kernel_launch(void* const* d_in, const int* in_sizes, int n_in,
                              void* d_out, int out_size, void* d_ws,
                              size_t ws_size, hipStream_t stream) {
  const float* xl = (const float*)d_in[0];
  const float* xm = (const float*)d_in[1];
  const float* Wq = (const float*)d_in[2];
  const float* bq = (const float*)d_in[3];
  const float* Wk = (const float*)d_in[4];
  const float* bk = (const float*)d_in[5];
  const float* W1 = (const float*)d_in[6];
  const float* b1 = (const float*)d_in[7];
  const float* W2 = (const float*)d_in[8];
  const float* b2 = (const float*)d_in[9];
  const float* Wo = (const float*)d_in[10];
  const float* bo = (const float*)d_in[11];
  float* outp = (float*)d_out;
  float* Tg = outp + 8192;  // [65536][256]: h f16 (bytes 0..511) + lie f16
                            // (bytes 512..751) per slot, then T fp32
  float* wsf = (float*)d_ws;
  float* Q = wsf;
  float* K = wsf + 65536;
  float* attn = wsf + 131072;  // 768 KB of ws used

  hipLaunchKernelGGL(qk_kernel, dim3(512), dim3(128), 0, stream, xl, Wq, bq, Wk, bk, Q, K);
  hipLaunchKernelGGL(attn_kernel, dim3(512), dim3(128), 0, stream, Q, K, attn);
  hipLaunchKernelGGL(h_kernel, dim3(1024), dim3(256), 0, stream, xl, W1, b1, (__half*)Tg);
  hipLaunchKernelGGL(lie_kernel, dim3(1024), dim3(256), 0, stream, W2, b2, Tg);
  hipLaunchKernelGGL(expm_kernel, dim3(8192), dim3(256), 0, stream, Tg);
  hipLaunchKernelGGL(settle_kernel, dim3(512), dim3(256), 0, stream, Tg, attn, xm, Wo, bo, outp);
}